// Round 8
// baseline (186.129 us; speedup 1.0000x reference)
//
#include <hip/hip_runtime.h>

// ---------------------------------------------------------------------------
// MultiScaleResidualVectorQuantize: 4-stage residual VQ, strides (8,4,2,1)
// e_i = P_i - sum_{j<i} tab_ij[idx_j]  with P_i = iw_i*pool_i(z)+ib_i and
// tab_ij[code] = M_ij*cb_j[code] + v_ij  (f64 precompute, f32 table).
// VQ scan is LDS-instruction-bound: records packed [1024][8] (2xb128/code)
// + cn2 batched (b128/4 codes) + 4 vectors/lane -> DS per vector-code /5.3.
// 7 launches: prep -> pool(+tabgen) -> vq0..3 -> zq.
// ---------------------------------------------------------------------------

constexpr int B = 16, D = 512, T = 4096, C = 8, K = 1024, NS = 4;

// output offsets (floats, concatenated in reference return order)
constexpr long long OUT_ZQ     = 0;                       // 16*512*4096
constexpr long long OUT_LAT    = 33554432LL;              // 16*32*4096
constexpr long long OUT_COMMIT = OUT_LAT + 2097152LL;     // 35651584
constexpr long long OUT_CBL    = OUT_COMMIT + 1;          // 35651585
constexpr long long OUT_CODES0 = OUT_CBL + 1;             // 35651586

__host__ __device__ constexpr long long code_off(int j) {
    return OUT_CODES0 + (j >= 1 ? 8192 : 0) + (j >= 2 ? 16384 : 0) + (j >= 3 ? 32768 : 0);
}

// workspace offsets (floats)
constexpr long long WS_CBREC = 0;                 // [4096][8] = -2*cn
constexpr long long WS_CN2   = 32768;             // [4096] cn2
constexpr long long WS_OBS   = 36864;             // 512 (sum of out biases)
constexpr long long WS_LOSS  = 37376;             // 1
constexpr long long WS_CORR  = 37384;             // doubles: 6 pairs * 72 (8B-aligned)
constexpr long long WS_P0    = 40960;             // 8192*8
constexpr long long WS_P1    = WS_P0 + 65536;
constexpr long long WS_P2    = WS_P1 + 131072;
constexpr long long WS_P3    = WS_P2 + 262144;
constexpr long long WS_Q0    = WS_P3 + 524288;
constexpr long long WS_Q1    = WS_Q0 + 65536;
constexpr long long WS_Q2    = WS_Q1 + 131072;
constexpr long long WS_Q3    = WS_Q2 + 262144;
constexpr long long WS_TAB   = WS_Q3 + 524288;    // 6*1024*8 f32; ends ~8.22MB

// ---------------------------------------------------------------------------
// k_prep: blocks 0..17 -> packed codebook records (-2cn [4096][8], cn2[4096])
// + summed bias + loss=0; blocks 18..125 -> correction terms M_ij/v_ij (f64).
// ---------------------------------------------------------------------------
__global__ __launch_bounds__(256) void k_prep(
    const float* __restrict__ in_w, const float* __restrict__ out_w,
    const float* __restrict__ out_b, const float* __restrict__ cb,
    float* __restrict__ ws)
{
    int bid = blockIdx.x;
    int tid = threadIdx.x;

    if (bid < 18) {
        int t = bid * 256 + tid;
        if (t == 0) ws[WS_LOSS] = 0.f;
        if (t < NS * K) {
            const float* c = cb + (long long)t * 8;
            float cv[8];
#pragma unroll
            for (int k = 0; k < 8; k++) cv[k] = c[k];
            float n2 = 0.f;
#pragma unroll
            for (int k = 0; k < 8; k++) n2 += cv[k] * cv[k];
            float den = fmaxf(sqrtf(n2), 1e-12f);
            float cn[8];
#pragma unroll
            for (int k = 0; k < 8; k++) cn[k] = cv[k] / den;
            float cn2 = 0.f;
#pragma unroll
            for (int k = 0; k < 8; k++) cn2 = fmaf(cn[k], cn[k], cn2);
            float* r = ws + WS_CBREC + (long long)t * 8;
#pragma unroll
            for (int k = 0; k < 8; k++) r[k] = -2.0f * cn[k];
            ws[WS_CN2 + t] = cn2;
        } else if (t < NS * K + D) {
            int d = t - NS * K;
            ws[WS_OBS + d] = out_b[d] + out_b[512 + d] + out_b[1024 + d] + out_b[1536 + d];
        }
        return;
    }

    int gw = (bid - 18) * 4 + (tid >> 6);
    int lane = tid & 63;
    if (gw >= 6 * 72) return;
    int p = gw / 72, idx = gw % 72;
    int i, j;
    if (p == 0) { i = 1; j = 0; }
    else if (p < 3) { i = 2; j = p - 1; }
    else { i = 3; j = p - 3; }

    double acc = 0.0;
    if (idx < 64) {
        int ci = idx >> 3, cc = idx & 7;
        const float* wi = in_w + (long long)(i * 8 + ci) * 512;
        const float* wo = out_w + (long long)j * 4096;      // [d][8]
#pragma unroll
        for (int k = 0; k < 8; k++) {
            int d = lane + k * 64;
            acc += (double)wi[d] * (double)wo[d * 8 + cc];
        }
    } else {
        int ci = idx - 64;
        const float* wi = in_w + (long long)(i * 8 + ci) * 512;
        const float* bo = out_b + (long long)j * 512;
#pragma unroll
        for (int k = 0; k < 8; k++) {
            int d = lane + k * 64;
            acc += (double)wi[d] * (double)bo[d];
        }
    }
#pragma unroll
    for (int off = 32; off >= 1; off >>= 1) acc += __shfl_down(acc, off);
    if (lane == 0) ((double*)(ws + WS_CORR))[p * 72 + idx] = acc;
}

// ---------------------------------------------------------------------------
// k_pool_proj v4: grid (16, 17). y<16: pool span of 256 t, lane owns 4 t
// (float4 z loads), 8 dseg waves; in_w LDS [d][36] with the reduction tree
// ALIASED into the same 72KB buffer -> 2 blocks/CU. y==16: tabgen tail
// (gather tables from WS_CORR, written by k_prep).
// ---------------------------------------------------------------------------
__global__ __launch_bounds__(512) void k_pool_proj(
    const float* __restrict__ z, const float* __restrict__ in_w,
    const float* __restrict__ in_b, const float* __restrict__ cb,
    float* __restrict__ ws)
{
    __shared__ float smem[512 * 36];     // 72 KB

    int tid = threadIdx.x;
    int lane = tid & 63;

    if (blockIdx.y == 16) {
        // ---- tabgen: tab[p][code][c] = v[p][c] + M[p][c][:]*cb_j[code] ----
        int t = blockIdx.x * 512 + tid;
        if (t < 6 * 1024) {
            int p = t >> 10, code = t & 1023;
            int j = (p == 0) ? 0 : (p < 3) ? (p - 1) : (p - 3);
            const double* M = (const double*)(ws + WS_CORR) + p * 72;
            const float* q = cb + ((long long)j * K + code) * 8;
            float qv[8];
#pragma unroll
            for (int cc = 0; cc < 8; cc++) qv[cc] = q[cc];
            float* trow = ws + WS_TAB + (long long)t * 8;
#pragma unroll
            for (int c = 0; c < 8; c++) {
                double acc = M[64 + c];
#pragma unroll
                for (int cc = 0; cc < 8; cc++) acc += M[c * 8 + cc] * (double)qv[cc];
                trow[c] = (float)acc;
            }
        }
        return;
    }

    int wv = __builtin_amdgcn_readfirstlane(tid >> 6);   // dseg, wave-uniform
    int b = blockIdx.x;
    int t0 = blockIdx.y * 256;

    // stage in_w -> LDS transposed
#pragma unroll
    for (int sc = 0; sc < 32; ++sc)
        smem[tid * 36 + sc] = in_w[sc * 512 + tid];
    __syncthreads();

    const float* zrow = z + ((long long)b * D) * T + t0 + lane * 4;

    float a3[4][8] = {};
    float a2[2][8] = {};
    float a1[8]    = {};
    float a0[8]    = {};

#pragma unroll 2
    for (int dd = 0; dd < 64; dd++) {
        int d = wv * 64 + dd;
        float4 v = *(const float4*)(zrow + (long long)d * T);
        const float* wrow = smem + d * 36;
        float w0[8], w1[8], w2[8], w3[8];
        *(float4*)&w0[0] = *(const float4*)(wrow + 0);
        *(float4*)&w0[4] = *(const float4*)(wrow + 4);
        *(float4*)&w1[0] = *(const float4*)(wrow + 8);
        *(float4*)&w1[4] = *(const float4*)(wrow + 12);
        *(float4*)&w2[0] = *(const float4*)(wrow + 16);
        *(float4*)&w2[4] = *(const float4*)(wrow + 20);
        *(float4*)&w3[0] = *(const float4*)(wrow + 24);
        *(float4*)&w3[4] = *(const float4*)(wrow + 28);

        float s2a = v.x + v.y, s2b = v.z + v.w;
        float s4 = s2a + s2b;
#pragma unroll
        for (int c = 0; c < 8; c++) {
            a3[0][c] = fmaf(w3[c], v.x, a3[0][c]);
            a3[1][c] = fmaf(w3[c], v.y, a3[1][c]);
            a3[2][c] = fmaf(w3[c], v.z, a3[2][c]);
            a3[3][c] = fmaf(w3[c], v.w, a3[3][c]);
            a2[0][c] = fmaf(w2[c], s2a, a2[0][c]);
            a2[1][c] = fmaf(w2[c], s2b, a2[1][c]);
            a1[c]    = fmaf(w1[c], s4, a1[c]);
            a0[c]    = fmaf(w0[c], s4, a0[c]);
        }
    }

    __syncthreads();   // done reading in_w slice; alias smem as tree

    // round 1: stage3 (32 slots) -- red[8][32][64] = 16384 floats (fits 18432)
    {
        float (*red)[32][64] = (float (*)[32][64])smem;
#pragma unroll
        for (int pos = 0; pos < 4; pos++)
#pragma unroll
            for (int c = 0; c < 8; c++)
                red[wv][pos * 8 + c][lane] = a3[pos][c];
        __syncthreads();
        for (int o = tid; o < 2048; o += 512) {
            int ln = o & 63, s = o >> 6;
            float sum = 0.f;
#pragma unroll
            for (int w = 0; w < 8; w++) sum += red[w][s][ln];
            int pos = s >> 3, c = s & 7;
            int tp = t0 + ln * 4 + pos;
            ws[WS_P3 + ((long long)b * 4096 + tp) * 8 + c] = sum + in_b[3 * 8 + c];
        }
        __syncthreads();
    }

    // round 2: stage2 (16 slots), stage1 (8), stage0 (8, lane pairs)
    {
        float (*red)[32][64] = (float (*)[32][64])smem;
#pragma unroll
        for (int pos = 0; pos < 2; pos++)
#pragma unroll
            for (int c = 0; c < 8; c++)
                red[wv][pos * 8 + c][lane] = a2[pos][c];
#pragma unroll
        for (int c = 0; c < 8; c++) {
            red[wv][16 + c][lane] = a1[c];
            red[wv][24 + c][lane] = a0[c];
        }
        __syncthreads();
        for (int o = tid; o < 2048; o += 512) {
            int ln = o & 63, s = o >> 6;
            if (s < 16) {
                float sum = 0.f;
#pragma unroll
                for (int w = 0; w < 8; w++) sum += red[w][s][ln];
                int pos = s >> 3, c = s & 7;
                int tp = (t0 >> 1) + ln * 2 + pos;
                ws[WS_P2 + ((long long)b * 2048 + tp) * 8 + c] = sum * 0.5f + in_b[2 * 8 + c];
            } else if (s < 24) {
                int c = s - 16;
                float sum = 0.f;
#pragma unroll
                for (int w = 0; w < 8; w++) sum += red[w][s][ln];
                int tp = (t0 >> 2) + ln;
                ws[WS_P1 + ((long long)b * 1024 + tp) * 8 + c] = sum * 0.25f + in_b[8 + c];
            } else {
                if (ln & 1) continue;
                int c = s - 24;
                float sum = 0.f;
#pragma unroll
                for (int w = 0; w < 8; w++) sum += red[w][s][ln] + red[w][s][ln + 1];
                int tp = (t0 >> 3) + (ln >> 1);
                ws[WS_P0 + ((long long)b * 512 + tp) * 8 + c] = sum * 0.125f + in_b[c];
            }
        }
    }
}

// ---------------------------------------------------------------------------
// k_vq<S>: block = 256 vectors (4 per lane) x 8 waves (512 thr). Records
// [1024][8] + cn2 batched (1 b128 per 4 codes) in LDS; scan = 2.25 DS + 44
// VALU per 4-vector code-step. First-index tie rules preserved (identical
// FMA order: acc starts at cn2, c=0..7). 56KB LDS.
// ---------------------------------------------------------------------------
template <int S>
__global__ __launch_bounds__(512) void k_vq(
    const float* __restrict__ cb, float* __restrict__ ws, float* __restrict__ out)
{
    constexpr int TS = 512 << S;
    constexpr long long PBASE = (S == 0) ? WS_P0 : (S == 1) ? WS_P1 : (S == 2) ? WS_P2 : WS_P3;
    constexpr long long QBASE = (S == 0) ? WS_Q0 : (S == 1) ? WS_Q1 : (S == 2) ? WS_Q2 : WS_Q3;
    constexpr int pbase = (S == 1) ? 0 : (S == 2) ? 1 : 3;
    constexpr float LW = 1.0f / (8.0f * (float)TS * (float)B);

    __shared__ float recl[1024 * 8];        // 32 KB
    __shared__ float cn2l[1024];            // 4 KB
    __shared__ float e_lds[256][8];         // 8 KB
    __shared__ float sbl[8][256];           // 8 KB
    __shared__ unsigned short sil[8][256];  // 4 KB

    int tid = threadIdx.x;
    int lane = tid & 63;
    int w = __builtin_amdgcn_readfirstlane(tid >> 6);
    int bid = blockIdx.x;

    // stage records + cn2 -> LDS
    {
        const float4* rs = (const float4*)(ws + WS_CBREC + (long long)S * 8192);
        float4* rd = (float4*)recl;
        for (int o = tid; o < 2048; o += 512) rd[o] = rs[o];
        const float4* cs = (const float4*)(ws + WS_CN2 + (long long)S * 1024);
        float4* cd = (float4*)cn2l;
        for (int o = tid; o < 256; o += 512) cd[o] = cs[o];
    }

    // e/en for this lane's 4 vectors (sv = h*64 + lane)
    float en[4][8];
#pragma unroll
    for (int h = 0; h < 4; h++) {
        int sv = h * 64 + lane;
        long long v = (long long)bid * 256 + sv;
        int b = (int)(v >> (9 + S));
        int tp = (int)(v & (TS - 1));

        float e[8];
        const float* P = ws + PBASE + v * 8;
#pragma unroll
        for (int c = 0; c < 8; c++) e[c] = P[c];

        if constexpr (S > 0) {
            double ed[8];
#pragma unroll
            for (int c = 0; c < 8; c++) ed[c] = (double)e[c];
#pragma unroll
            for (int j = 0; j < S; j++) {
                int tj = tp >> (S - j);
                long long vj = ((long long)b << (9 + j)) + tj;
                int cidx = (int)out[code_off(j) + vj];
                const float* trow = ws + WS_TAB + ((long long)(pbase + j) * 1024 + cidx) * 8;
#pragma unroll
                for (int c = 0; c < 8; c++) ed[c] -= (double)trow[c];
            }
#pragma unroll
            for (int c = 0; c < 8; c++) e[c] = (float)ed[c];
        }

        float n2 = 0.f;
#pragma unroll
        for (int c = 0; c < 8; c++) n2 = fmaf(e[c], e[c], n2);
        float den = fmaxf(sqrtf(n2), 1e-12f);
        float inv = 1.0f / den;
#pragma unroll
        for (int c = 0; c < 8; c++) en[h][c] = e[c] * inv;
        if (w == 0) {
#pragma unroll
            for (int c = 0; c < 8; c++) e_lds[sv][c] = e[c];
        }
    }

    __syncthreads();   // records + e_lds ready

    // scan this wave's 128-code chunk for 4 vectors
    const float* rec = recl + w * 128 * 8;
    const float* c2  = cn2l + w * 128;
    float best0 = 3.0e38f, best1 = 3.0e38f, best2 = 3.0e38f, best3 = 3.0e38f;
    int bi0 = 0, bi1 = 0, bi2 = 0, bi3 = 0;

    for (int j0 = 0; j0 < 128; j0 += 4) {
        float4 cq = *(const float4*)(c2 + j0);
        float cqa[4] = { cq.x, cq.y, cq.z, cq.w };
#pragma unroll
        for (int k = 0; k < 4; k++) {
            int jt = j0 + k;
            const float* r = rec + jt * 8;
            float rr[8];
            *(float4*)&rr[0] = *(const float4*)(r + 0);
            *(float4*)&rr[4] = *(const float4*)(r + 4);
            float cc = cqa[k];
            float a0 = cc, a1 = cc, a2 = cc, a3 = cc;
#pragma unroll
            for (int c = 0; c < 8; c++) {
                float rc = rr[c];
                a0 = fmaf(rc, en[0][c], a0);
                a1 = fmaf(rc, en[1][c], a1);
                a2 = fmaf(rc, en[2][c], a2);
                a3 = fmaf(rc, en[3][c], a3);
            }
            if (a0 < best0) { best0 = a0; bi0 = jt; }
            if (a1 < best1) { best1 = a1; bi1 = jt; }
            if (a2 < best2) { best2 = a2; bi2 = jt; }
            if (a3 < best3) { best3 = a3; bi3 = jt; }
        }
    }

    sbl[w][lane]       = best0;  sil[w][lane]       = (unsigned short)(w * 128 + bi0);
    sbl[w][64 + lane]  = best1;  sil[w][64 + lane]  = (unsigned short)(w * 128 + bi1);
    sbl[w][128 + lane] = best2;  sil[w][128 + lane] = (unsigned short)(w * 128 + bi2);
    sbl[w][192 + lane] = best3;  sil[w][192 + lane] = (unsigned short)(w * 128 + bi3);
    __syncthreads();

    if (tid < 256) {
        int sv = tid;
        float bd = sbl[0][sv];
        int bj = sil[0][sv];
#pragma unroll
        for (int ww = 1; ww < 8; ww++) {
            float d2 = sbl[ww][sv];
            int j2 = sil[ww][sv];
            if (d2 < bd || (d2 == bd && j2 < bj)) { bd = d2; bj = j2; }
        }
        long long v = (long long)bid * 256 + sv;
        // unnormalized codebook lookup
        const float* qc = cb + ((long long)S * K + bj) * 8;
        float qv[8];
#pragma unroll
        for (int c = 0; c < 8; c++) qv[c] = qc[c];
        float* qo = ws + QBASE + v * 8;
#pragma unroll
        for (int c = 0; c < 8; c++) qo[c] = qv[c];

        out[code_off(S) + v] = (float)bj;

        // commit/cb loss (identical values)
        float l = 0.f;
#pragma unroll
        for (int c = 0; c < 8; c++) { float dq = e_lds[sv][c] - qv[c]; l = fmaf(dq, dq, l); }
#pragma unroll
        for (int off = 32; off >= 1; off >>= 1) l += __shfl_down(l, off);
        if ((tid & 63) == 0) atomicAdd(ws + WS_LOSS, l * LW);
    }

    // cooperative latents write (float4), 256 vectors * 8c * SREP floats
    constexpr int SREP = 8 >> S;
    constexpr int SH = 3 - S;
    {
        long long v0 = (long long)bid * 256;
        int b0 = (int)(v0 >> (9 + S));
        int tp0 = (int)(v0 & (TS - 1));
        long long lat0 = OUT_LAT + ((long long)b0 * 32 + S * 8) * T + (long long)tp0 * SREP;
        for (int o = tid; o < 512 * SREP; o += 512) {
            int c = o / (64 * SREP);
            int i4 = o % (64 * SREP);
            int r0 = i4 * 4;
            float4 vv = make_float4(
                e_lds[(r0 + 0) >> SH][c], e_lds[(r0 + 1) >> SH][c],
                e_lds[(r0 + 2) >> SH][c], e_lds[(r0 + 3) >> SH][c]);
            *(float4*)(out + lat0 + (long long)c * T + r0) = vv;
        }
    }
}

// ---------------------------------------------------------------------------
// k_zq: lane owns 4 consecutive t -> float4 stores; 4096 blocks.
// ---------------------------------------------------------------------------
__global__ __launch_bounds__(256) void k_zq(
    const float* __restrict__ out_w, const float* __restrict__ ws, float* __restrict__ out)
{
    int tid = threadIdx.x;
    int lane = tid & 63;
    int w = __builtin_amdgcn_readfirstlane(tid >> 6);
    int bid = blockIdx.x;                 // 4096 = 16 b * 64 dgrp * 4 tchunk
    int tc   = bid & 3;
    int g    = (bid >> 2) & 63;
    int b    = bid >> 8;
    int t    = tc * 1024 + w * 256 + lane * 4;

    float q0[8], q1[8], q2[2][8], q3[4][8];
    {
        const float* Q = ws + WS_Q0 + ((long long)b * 512 + (t >> 3)) * 8;
#pragma unroll
        for (int c = 0; c < 8; c++) q0[c] = Q[c];
    }
    {
        const float* Q = ws + WS_Q1 + ((long long)b * 1024 + (t >> 2)) * 8;
#pragma unroll
        for (int c = 0; c < 8; c++) q1[c] = Q[c];
    }
    {
        const float* Q = ws + WS_Q2 + ((long long)b * 2048 + (t >> 1)) * 8;
#pragma unroll
        for (int j = 0; j < 2; j++)
#pragma unroll
            for (int c = 0; c < 8; c++) q2[j][c] = Q[j * 8 + c];
    }
    {
        const float* Q = ws + WS_Q3 + ((long long)b * 4096 + t) * 8;
#pragma unroll
        for (int j = 0; j < 4; j++)
#pragma unroll
            for (int c = 0; c < 8; c++) q3[j][c] = Q[j * 8 + c];
    }

#pragma unroll 2
    for (int dl = 0; dl < 8; dl++) {
        int d = g * 8 + dl;
        const float* w0 = out_w + 0 * 4096 + d * 8;
        const float* w1 = out_w + 1 * 4096 + d * 8;
        const float* w2 = out_w + 2 * 4096 + d * 8;
        const float* w3 = out_w + 3 * 4096 + d * 8;

        float acc = ws[WS_OBS + d];
#pragma unroll
        for (int c = 0; c < 8; c++) acc = fmaf(w0[c], q0[c], acc);
#pragma unroll
        for (int c = 0; c < 8; c++) acc = fmaf(w1[c], q1[c], acc);
        float accA = acc, accB = acc;
#pragma unroll
        for (int c = 0; c < 8; c++) {
            accA = fmaf(w2[c], q2[0][c], accA);
            accB = fmaf(w2[c], q2[1][c], accB);
        }
        float r0 = accA, r1 = accA, r2 = accB, r3 = accB;
#pragma unroll
        for (int c = 0; c < 8; c++) {
            r0 = fmaf(w3[c], q3[0][c], r0);
            r1 = fmaf(w3[c], q3[1][c], r1);
            r2 = fmaf(w3[c], q3[2][c], r2);
            r3 = fmaf(w3[c], q3[3][c], r3);
        }
        float* o = out + OUT_ZQ + ((long long)b * 512 + d) * T + t;
        *(float4*)o = make_float4(r0, r1, r2, r3);
    }

    if (bid == 0 && tid == 0) {
        float L = ws[WS_LOSS];
        out[OUT_COMMIT] = L;
        out[OUT_CBL]    = L;
    }
}

// ---------------------------------------------------------------------------
extern "C" void kernel_launch(void* const* d_in, const int* in_sizes, int n_in,
                              void* d_out, int out_size, void* d_ws, size_t ws_size,
                              hipStream_t stream)
{
    const float* z     = (const float*)d_in[0];
    const float* in_w  = (const float*)d_in[1];
    const float* in_b  = (const float*)d_in[2];
    const float* out_w = (const float*)d_in[3];
    const float* out_b = (const float*)d_in[4];
    const float* cb    = (const float*)d_in[5];
    float* out = (float*)d_out;
    float* ws  = (float*)d_ws;

    k_prep<<<dim3(126), dim3(256), 0, stream>>>(in_w, out_w, out_b, cb, ws);
    k_pool_proj<<<dim3(16, 17), dim3(512), 0, stream>>>(z, in_w, in_b, cb, ws);
    k_vq<0><<<dim3(32),  dim3(512), 0, stream>>>(cb, ws, out);
    k_vq<1><<<dim3(64),  dim3(512), 0, stream>>>(cb, ws, out);
    k_vq<2><<<dim3(128), dim3(512), 0, stream>>>(cb, ws, out);
    k_vq<3><<<dim3(256), dim3(512), 0, stream>>>(cb, ws, out);
    k_zq<<<dim3(4096), dim3(256), 0, stream>>>(out_w, ws, out);
}

// Round 9
// 164.905 us; speedup vs baseline: 1.1287x; 1.1287x over previous
//
#include <hip/hip_runtime.h>

// ---------------------------------------------------------------------------
// MultiScaleResidualVectorQuantize: 4-stage residual VQ, strides (8,4,2,1)
// e_i = P_i - sum_{j<i} tab_ij[idx_j];  P_i = iw_i*pool_i(z)+ib_i;
// tab_ij[code] = M_ij*cb_j[code]+v_ij (f64 precompute, f32 table).
// VQ: per stage, en-compute once (k_en, in-place on P) -> code-split scan
// (256 vectors x F=8>>S code-chunk blocks = 256 blocks/stage, VPL=4,
// in-block LDS merge + packed-u64 atomicMin for exact first-index ties)
// -> emit (codes+loss) -> zq gathers q from cb via keys.
// ---------------------------------------------------------------------------

constexpr int B = 16, D = 512, T = 4096, C = 8, K = 1024, NS = 4;

// output offsets (floats, reference return order)
constexpr long long OUT_ZQ     = 0;                       // 16*512*4096
constexpr long long OUT_LAT    = 33554432LL;              // 16*32*4096
constexpr long long OUT_COMMIT = OUT_LAT + 2097152LL;
constexpr long long OUT_CBL    = OUT_COMMIT + 1;
constexpr long long OUT_CODES0 = OUT_CBL + 1;

__host__ __device__ constexpr long long code_off(int j) {
    return OUT_CODES0 + (j >= 1 ? 8192 : 0) + (j >= 2 ? 16384 : 0) + (j >= 3 ? 32768 : 0);
}

// workspace offsets (floats)
constexpr long long WS_CBREC = 0;                 // [4096][8] = -2*cn
constexpr long long WS_CN2   = 32768;             // [4096]
constexpr long long WS_OBS   = 36864;             // 512
constexpr long long WS_LOSS  = 37376;             // 1
constexpr long long WS_CORR  = 37384;             // 1152 doubles (8B aligned)
constexpr long long WS_P0    = 40960;             // 8192*8   (becomes E0)
constexpr long long WS_P1    = WS_P0 + 65536;     // (becomes E1)
constexpr long long WS_P2    = WS_P1 + 131072;
constexpr long long WS_P3    = WS_P2 + 262144;
constexpr long long WS_TAB   = WS_P3 + 524288;    // 6*1024*8
constexpr long long WS_KEY   = WS_TAB + 49152;    // 122880 u64; ends ~5.3MB

__host__ __device__ constexpr long long key_off(int s) {  // u64 units
    return (s >= 1 ? 8192 : 0) + (s >= 2 ? 16384 : 0) + (s >= 3 ? 32768 : 0);
}
__host__ __device__ constexpr long long pbase_of(int s) {
    return (s == 0) ? WS_P0 : (s == 1) ? WS_P1 : (s == 2) ? WS_P2 : WS_P3;
}

// ---------------------------------------------------------------------------
// k_prep: blocks 0..17 packed records (-2cn, cn2) + obs + loss=0;
// blocks 18..125 correction terms M_ij/v_ij (f64, one wave per scalar).
// ---------------------------------------------------------------------------
__global__ __launch_bounds__(256) void k_prep(
    const float* __restrict__ in_w, const float* __restrict__ out_w,
    const float* __restrict__ out_b, const float* __restrict__ cb,
    float* __restrict__ ws)
{
    int bid = blockIdx.x;
    int tid = threadIdx.x;

    if (bid < 18) {
        int t = bid * 256 + tid;
        if (t == 0) ws[WS_LOSS] = 0.f;
        if (t < NS * K) {
            const float* c = cb + (long long)t * 8;
            float cv[8];
#pragma unroll
            for (int k = 0; k < 8; k++) cv[k] = c[k];
            float n2 = 0.f;
#pragma unroll
            for (int k = 0; k < 8; k++) n2 += cv[k] * cv[k];
            float den = fmaxf(sqrtf(n2), 1e-12f);
            float cn[8];
#pragma unroll
            for (int k = 0; k < 8; k++) cn[k] = cv[k] / den;
            float cn2 = 0.f;
#pragma unroll
            for (int k = 0; k < 8; k++) cn2 = fmaf(cn[k], cn[k], cn2);
            float* r = ws + WS_CBREC + (long long)t * 8;
#pragma unroll
            for (int k = 0; k < 8; k++) r[k] = -2.0f * cn[k];
            ws[WS_CN2 + t] = cn2;
        } else if (t < NS * K + D) {
            int d = t - NS * K;
            ws[WS_OBS + d] = out_b[d] + out_b[512 + d] + out_b[1024 + d] + out_b[1536 + d];
        }
        return;
    }

    int gw = (bid - 18) * 4 + (tid >> 6);
    int lane = tid & 63;
    if (gw >= 6 * 72) return;
    int p = gw / 72, idx = gw % 72;
    int i, j;
    if (p == 0) { i = 1; j = 0; }
    else if (p < 3) { i = 2; j = p - 1; }
    else { i = 3; j = p - 3; }

    double acc = 0.0;
    if (idx < 64) {
        int ci = idx >> 3, cc = idx & 7;
        const float* wi = in_w + (long long)(i * 8 + ci) * 512;
        const float* wo = out_w + (long long)j * 4096;      // [d][8]
#pragma unroll
        for (int k = 0; k < 8; k++) {
            int d = lane + k * 64;
            acc += (double)wi[d] * (double)wo[d * 8 + cc];
        }
    } else {
        int ci = idx - 64;
        const float* wi = in_w + (long long)(i * 8 + ci) * 512;
        const float* bo = out_b + (long long)j * 512;
#pragma unroll
        for (int k = 0; k < 8; k++) {
            int d = lane + k * 64;
            acc += (double)wi[d] * (double)bo[d];
        }
    }
#pragma unroll
    for (int off = 32; off >= 1; off >>= 1) acc += __shfl_down(acc, off);
    if (lane == 0) ((double*)(ws + WS_CORR))[p * 72 + idx] = acc;
}

// ---------------------------------------------------------------------------
// k_prep_c: blocks 0..23 tabgen (needs CORR); blocks 24..503 key init (~0u64).
// ---------------------------------------------------------------------------
__global__ __launch_bounds__(256) void k_prep_c(
    const float* __restrict__ cb, float* __restrict__ ws)
{
    int bid = blockIdx.x;
    int tid = threadIdx.x;
    if (bid < 24) {
        int t = bid * 256 + tid;
        if (t < 6 * 1024) {
            int p = t >> 10, code = t & 1023;
            int j = (p == 0) ? 0 : (p < 3) ? (p - 1) : (p - 3);
            const double* M = (const double*)(ws + WS_CORR) + p * 72;
            const float* q = cb + ((long long)j * K + code) * 8;
            float qv[8];
#pragma unroll
            for (int cc = 0; cc < 8; cc++) qv[cc] = q[cc];
            float* trow = ws + WS_TAB + (long long)t * 8;
#pragma unroll
            for (int c = 0; c < 8; c++) {
                double acc = M[64 + c];
#pragma unroll
                for (int cc = 0; cc < 8; cc++) acc += M[c * 8 + cc] * (double)qv[cc];
                trow[c] = (float)acc;
            }
        }
    } else {
        long long o = (long long)(bid - 24) * 256 + tid;
        if (o < 122880)
            ((unsigned long long*)(ws + WS_KEY))[o] = 0xFFFFFFFFFFFFFFFFULL;
    }
}

// ---------------------------------------------------------------------------
// k_pool_proj (R6 v3, proven): block = (b, 128-t span), 512 thr; in_w LDS
// [d][36] with reduction tree aliased into the same 72KB. Grid 16x32.
// ---------------------------------------------------------------------------
__global__ __launch_bounds__(512) void k_pool_proj(
    const float* __restrict__ z, const float* __restrict__ in_w,
    const float* __restrict__ in_b, float* __restrict__ ws)
{
    __shared__ float smem[512 * 36];     // 72 KB

    int tid = threadIdx.x;
    int lane = tid & 63;
    int wv = __builtin_amdgcn_readfirstlane(tid >> 6);
    int b = blockIdx.x;
    int t0 = blockIdx.y * 128;

#pragma unroll
    for (int sc = 0; sc < 32; ++sc)
        smem[tid * 36 + sc] = in_w[sc * 512 + tid];
    __syncthreads();

    const float* zrow = z + ((long long)b * D) * T + t0 + lane * 2;

    float a3[2][8] = {};
    float a2[8]    = {};
    float a1[8]    = {};
    float a0[8]    = {};

#pragma unroll 2
    for (int dd = 0; dd < 64; dd++) {
        int d = wv * 64 + dd;
        float2 v = *(const float2*)(zrow + (long long)d * T);
        const float* wrow = smem + d * 36;
        float w0[8], w1[8], w2[8], w3[8];
        *(float4*)&w0[0] = *(const float4*)(wrow + 0);
        *(float4*)&w0[4] = *(const float4*)(wrow + 4);
        *(float4*)&w1[0] = *(const float4*)(wrow + 8);
        *(float4*)&w1[4] = *(const float4*)(wrow + 12);
        *(float4*)&w2[0] = *(const float4*)(wrow + 16);
        *(float4*)&w2[4] = *(const float4*)(wrow + 20);
        *(float4*)&w3[0] = *(const float4*)(wrow + 24);
        *(float4*)&w3[4] = *(const float4*)(wrow + 28);

        float s2 = v.x + v.y;
#pragma unroll
        for (int c = 0; c < 8; c++) {
            a3[0][c] = fmaf(w3[c], v.x, a3[0][c]);
            a3[1][c] = fmaf(w3[c], v.y, a3[1][c]);
            a2[c]    = fmaf(w2[c], s2, a2[c]);
            a1[c]    = fmaf(w1[c], s2, a1[c]);
            a0[c]    = fmaf(w0[c], s2, a0[c]);
        }
    }

    __syncthreads();

    {
        float (*red)[16][64] = (float (*)[16][64])smem;
#pragma unroll
        for (int pos = 0; pos < 2; pos++)
#pragma unroll
            for (int c = 0; c < 8; c++)
                red[wv][pos * 8 + c][lane] = a3[pos][c];
        __syncthreads();
        for (int o = tid; o < 1024; o += 512) {
            int ln = o & 63, s = o >> 6;
            float sum = 0.f;
#pragma unroll
            for (int w = 0; w < 8; w++) sum += red[w][s][ln];
            int pos = s >> 3, c = s & 7;
            int tp = t0 + ln * 2 + pos;
            ws[WS_P3 + ((long long)b * 4096 + tp) * 8 + c] = sum + in_b[3 * 8 + c];
        }
        __syncthreads();
    }

    {
        float (*red)[24][64] = (float (*)[24][64])smem;
#pragma unroll
        for (int c = 0; c < 8; c++) {
            red[wv][c][lane]      = a2[c];
            red[wv][8 + c][lane]  = a1[c];
            red[wv][16 + c][lane] = a0[c];
        }
        __syncthreads();
        for (int o = tid; o < 1536; o += 512) {
            int ln = o & 63, s = o >> 6;
            if (s < 8) {
                int c = s;
                float sum = 0.f;
#pragma unroll
                for (int w = 0; w < 8; w++) sum += red[w][s][ln];
                int tp = (t0 >> 1) + ln;
                ws[WS_P2 + ((long long)b * 2048 + tp) * 8 + c] = sum * 0.5f + in_b[2 * 8 + c];
            } else if (s < 16) {
                if (ln >= 32) continue;
                int c = s - 8;
                float sum = 0.f;
#pragma unroll
                for (int w = 0; w < 8; w++) sum += red[w][s][2 * ln] + red[w][s][2 * ln + 1];
                int tp = (t0 >> 2) + ln;
                ws[WS_P1 + ((long long)b * 1024 + tp) * 8 + c] = sum * 0.25f + in_b[8 + c];
            } else {
                if (ln >= 16) continue;
                int c = s - 16;
                float sum = 0.f;
#pragma unroll
                for (int w = 0; w < 8; w++)
#pragma unroll
                    for (int k = 0; k < 4; k++) sum += red[w][s][4 * ln + k];
                int tp = (t0 >> 3) + ln;
                ws[WS_P0 + ((long long)b * 512 + tp) * 8 + c] = sum * 0.125f + in_b[c];
            }
        }
    }
}

// ---------------------------------------------------------------------------
// k_en<S>: one thread per vector. E = P - corrections (f64, idx from keys of
// earlier stages), written IN PLACE on P; latents written from registers
// (consecutive lanes = consecutive t -> coalesced). S=0: latents only.
// ---------------------------------------------------------------------------
template <int S>
__global__ __launch_bounds__(512) void k_en(
    float* __restrict__ ws, float* __restrict__ out)
{
    constexpr int TS = 512 << S;
    constexpr long long EBASE = pbase_of(S);
    constexpr int pbase = (S == 1) ? 0 : (S == 2) ? 1 : 3;
    constexpr int SREP = 8 >> S;

    long long v = (long long)blockIdx.x * 512 + threadIdx.x;
    int b = (int)(v >> (9 + S));
    int tp = (int)(v & (TS - 1));

    float e[8];
    float* E = ws + EBASE + v * 8;
    *(float4*)&e[0] = *(const float4*)(E + 0);
    *(float4*)&e[4] = *(const float4*)(E + 4);

    if constexpr (S > 0) {
        const unsigned long long* keys = (const unsigned long long*)(ws + WS_KEY);
        double ed[8];
#pragma unroll
        for (int c = 0; c < 8; c++) ed[c] = (double)e[c];
#pragma unroll
        for (int j = 0; j < S; j++) {
            int tj = tp >> (S - j);
            long long vj = ((long long)b << (9 + j)) + tj;
            int cidx = (int)(unsigned)keys[key_off(j) + vj];
            const float* trow = ws + WS_TAB + ((long long)(pbase + j) * 1024 + cidx) * 8;
#pragma unroll
            for (int c = 0; c < 8; c++) ed[c] -= (double)trow[c];
        }
#pragma unroll
        for (int c = 0; c < 8; c++) e[c] = (float)ed[c];
        *(float4*)(E + 0) = *(const float4*)&e[0];
        *(float4*)(E + 4) = *(const float4*)&e[4];
    }

    // latents
    long long lat0 = OUT_LAT + ((long long)b * 32 + S * 8) * T + (long long)tp * SREP;
#pragma unroll
    for (int c = 0; c < 8; c++) {
        float* o = out + lat0 + (long long)c * T;
        if constexpr (SREP == 8) {
            float4 fv = make_float4(e[c], e[c], e[c], e[c]);
            *(float4*)(o + 0) = fv;
            *(float4*)(o + 4) = fv;
        } else if constexpr (SREP == 4) {
            *(float4*)o = make_float4(e[c], e[c], e[c], e[c]);
        } else if constexpr (SREP == 2) {
            *(float2*)o = make_float2(e[c], e[c]);
        } else {
            *o = e[c];
        }
    }
}

// ---------------------------------------------------------------------------
// k_scan<S>: grid (F=8>>S, NVEC/256). Block = 256 vectors x (1024/F)-code
// chunk; 8 waves split the chunk (CPW codes each), each lane owns 4 vectors.
// Records in LDS; in-block LDS merge; one atomicMin(u64 key) per vector.
// Key = monotone(dist)<<32 | code -> exact first-index tie semantics.
// ---------------------------------------------------------------------------
template <int S>
__global__ __launch_bounds__(512) void k_scan(float* __restrict__ ws)
{
    constexpr int F = 8 >> S;
    constexpr int CHUNK = 1024 / F;
    constexpr int CPW = CHUNK / 8;
    constexpr long long EBASE = pbase_of(S);

    __shared__ float recl[CHUNK * 8];
    __shared__ float cn2l[CHUNK];
    __shared__ float sbl[8][256];
    __shared__ unsigned short sil[8][256];

    int tid = threadIdx.x;
    int lane = tid & 63;
    int w = __builtin_amdgcn_readfirstlane(tid >> 6);
    int ck = blockIdx.x;          // code chunk
    int vb = blockIdx.y;          // vector block

    // stage chunk records -> LDS
    {
        const float4* rs = (const float4*)(ws + WS_CBREC + (long long)S * 8192 + (long long)ck * CHUNK * 8);
        float4* rd = (float4*)recl;
        for (int o = tid; o < CHUNK * 2; o += 512) rd[o] = rs[o];
        const float4* cs = (const float4*)(ws + WS_CN2 + (long long)S * 1024 + (long long)ck * CHUNK);
        float4* cd = (float4*)cn2l;
        for (int o = tid; o < CHUNK / 4; o += 512) cd[o] = cs[o];
    }

    // load + normalize this lane's 4 vectors
    float en[4][8];
#pragma unroll
    for (int h = 0; h < 4; h++) {
        long long v = (long long)vb * 256 + h * 64 + lane;
        const float* E = ws + EBASE + v * 8;
        float e[8];
        *(float4*)&e[0] = *(const float4*)(E + 0);
        *(float4*)&e[4] = *(const float4*)(E + 4);
        float n2 = 0.f;
#pragma unroll
        for (int c = 0; c < 8; c++) n2 = fmaf(e[c], e[c], n2);
        float den = fmaxf(sqrtf(n2), 1e-12f);
        float inv = 1.0f / den;
#pragma unroll
        for (int c = 0; c < 8; c++) en[h][c] = e[c] * inv;
    }

    __syncthreads();

    // scan this wave's CPW-code sub-chunk for 4 vectors
    const float* rec = recl + w * CPW * 8;
    const float* c2  = cn2l + w * CPW;
    float best0 = 3.0e38f, best1 = 3.0e38f, best2 = 3.0e38f, best3 = 3.0e38f;
    int bi0 = 0, bi1 = 0, bi2 = 0, bi3 = 0;

    for (int j0 = 0; j0 < CPW; j0 += 4) {
        float4 cq = *(const float4*)(c2 + j0);
        float cqa[4] = { cq.x, cq.y, cq.z, cq.w };
#pragma unroll
        for (int k = 0; k < 4; k++) {
            int jt = j0 + k;
            const float* r = rec + jt * 8;
            float rr[8];
            *(float4*)&rr[0] = *(const float4*)(r + 0);
            *(float4*)&rr[4] = *(const float4*)(r + 4);
            float cc = cqa[k];
            float a0 = cc, a1 = cc, a2 = cc, a3 = cc;
#pragma unroll
            for (int c = 0; c < 8; c++) {
                float rc = rr[c];
                a0 = fmaf(rc, en[0][c], a0);
                a1 = fmaf(rc, en[1][c], a1);
                a2 = fmaf(rc, en[2][c], a2);
                a3 = fmaf(rc, en[3][c], a3);
            }
            if (a0 < best0) { best0 = a0; bi0 = jt; }
            if (a1 < best1) { best1 = a1; bi1 = jt; }
            if (a2 < best2) { best2 = a2; bi2 = jt; }
            if (a3 < best3) { best3 = a3; bi3 = jt; }
        }
    }

    sbl[w][lane]       = best0;  sil[w][lane]       = (unsigned short)(w * CPW + bi0);
    sbl[w][64 + lane]  = best1;  sil[w][64 + lane]  = (unsigned short)(w * CPW + bi1);
    sbl[w][128 + lane] = best2;  sil[w][128 + lane] = (unsigned short)(w * CPW + bi2);
    sbl[w][192 + lane] = best3;  sil[w][192 + lane] = (unsigned short)(w * CPW + bi3);
    __syncthreads();

    if (tid < 256) {
        int sv = tid;
        float bd = sbl[0][sv];
        int bj = sil[0][sv];
#pragma unroll
        for (int ww = 1; ww < 8; ww++) {
            float d2 = sbl[ww][sv];
            int j2 = sil[ww][sv];
            if (d2 < bd || (d2 == bd && j2 < bj)) { bd = d2; bj = j2; }
        }
        int code = ck * CHUNK + bj;
        unsigned u = __float_as_uint(bd);
        u = (u & 0x80000000u) ? ~u : (u | 0x80000000u);
        unsigned long long key = ((unsigned long long)u << 32) | (unsigned)code;
        long long v = (long long)vb * 256 + sv;
        atomicMin((unsigned long long*)(ws + WS_KEY) + key_off(S) + v, key);
    }
}

// ---------------------------------------------------------------------------
// k_emit: one thread per vector (480 blocks x 256; block boundaries align to
// stages). codes + loss from keys + E + cb.
// ---------------------------------------------------------------------------
__global__ __launch_bounds__(256) void k_emit(
    const float* __restrict__ cb, float* __restrict__ ws, float* __restrict__ out)
{
    int bid = blockIdx.x;
    int tid = threadIdx.x;
    long long t = (long long)bid * 256 + tid;

    int S = (t < 8192) ? 0 : (t < 24576) ? 1 : (t < 57344) ? 2 : 3;
    long long base = (S == 0) ? 0 : (S == 1) ? 8192 : (S == 2) ? 24576 : 57344;
    long long v = t - base;
    long long ebase = (S == 0) ? WS_P0 : (S == 1) ? WS_P1 : (S == 2) ? WS_P2 : WS_P3;

    unsigned long long key = ((const unsigned long long*)(ws + WS_KEY))[base + v];
    int bj = (int)(unsigned)key;

    out[code_off(S) + v] = (float)bj;

    const float* E = ws + ebase + v * 8;
    const float* qc = cb + ((long long)S * K + bj) * 8;
    float l = 0.f;
#pragma unroll
    for (int c = 0; c < 8; c++) {
        float dq = E[c] - qc[c];
        l = fmaf(dq, dq, l);
    }
    float LW = 1.0f / (float)(65536 << S);   // 1/(8 * TS * B)
    l *= LW;
#pragma unroll
    for (int off = 32; off >= 1; off >>= 1) l += __shfl_down(l, off);
    if ((tid & 63) == 0) atomicAdd(ws + WS_LOSS, l);
}

// ---------------------------------------------------------------------------
// k_zq: lane owns 4 consecutive t -> float4 stores; q gathered from cb via
// keys. 4096 blocks. Same FMA chain as before (bit-identical z_q).
// ---------------------------------------------------------------------------
__global__ __launch_bounds__(256) void k_zq(
    const float* __restrict__ out_w, const float* __restrict__ cb,
    const float* __restrict__ ws, float* __restrict__ out)
{
    int tid = threadIdx.x;
    int lane = tid & 63;
    int w = __builtin_amdgcn_readfirstlane(tid >> 6);
    int bid = blockIdx.x;                 // 4096 = 16 b * 64 dgrp * 4 tchunk
    int tc   = bid & 3;
    int g    = (bid >> 2) & 63;
    int b    = bid >> 8;
    int t    = tc * 1024 + w * 256 + lane * 4;

    const unsigned long long* keys = (const unsigned long long*)(ws + WS_KEY);

    float q0[8], q1[8], q2[2][8], q3[4][8];
    {
        int bj = (int)(unsigned)keys[key_off(0) + (long long)b * 512 + (t >> 3)];
        const float* Q = cb + (long long)bj * 8;
#pragma unroll
        for (int c = 0; c < 8; c++) q0[c] = Q[c];
    }
    {
        int bj = (int)(unsigned)keys[key_off(1) + (long long)b * 1024 + (t >> 2)];
        const float* Q = cb + (long long)(K + bj) * 8;
#pragma unroll
        for (int c = 0; c < 8; c++) q1[c] = Q[c];
    }
#pragma unroll
    for (int j = 0; j < 2; j++) {
        int bj = (int)(unsigned)keys[key_off(2) + (long long)b * 2048 + (t >> 1) + j];
        const float* Q = cb + (long long)(2 * K + bj) * 8;
#pragma unroll
        for (int c = 0; c < 8; c++) q2[j][c] = Q[c];
    }
#pragma unroll
    for (int j = 0; j < 4; j++) {
        int bj = (int)(unsigned)keys[key_off(3) + (long long)b * 4096 + t + j];
        const float* Q = cb + (long long)(3 * K + bj) * 8;
#pragma unroll
        for (int c = 0; c < 8; c++) q3[j][c] = Q[c];
    }

#pragma unroll 2
    for (int dl = 0; dl < 8; dl++) {
        int d = g * 8 + dl;
        const float* w0 = out_w + 0 * 4096 + d * 8;
        const float* w1 = out_w + 1 * 4096 + d * 8;
        const float* w2 = out_w + 2 * 4096 + d * 8;
        const float* w3 = out_w + 3 * 4096 + d * 8;

        float acc = ws[WS_OBS + d];
#pragma unroll
        for (int c = 0; c < 8; c++) acc = fmaf(w0[c], q0[c], acc);
#pragma unroll
        for (int c = 0; c < 8; c++) acc = fmaf(w1[c], q1[c], acc);
        float accA = acc, accB = acc;
#pragma unroll
        for (int c = 0; c < 8; c++) {
            accA = fmaf(w2[c], q2[0][c], accA);
            accB = fmaf(w2[c], q2[1][c], accB);
        }
        float r0 = accA, r1 = accA, r2 = accB, r3 = accB;
#pragma unroll
        for (int c = 0; c < 8; c++) {
            r0 = fmaf(w3[c], q3[0][c], r0);
            r1 = fmaf(w3[c], q3[1][c], r1);
            r2 = fmaf(w3[c], q3[2][c], r2);
            r3 = fmaf(w3[c], q3[3][c], r3);
        }
        float* o = out + OUT_ZQ + ((long long)b * 512 + d) * T + t;
        *(float4*)o = make_float4(r0, r1, r2, r3);
    }

    if (bid == 0 && tid == 0) {
        float L = ws[WS_LOSS];
        out[OUT_COMMIT] = L;
        out[OUT_CBL]    = L;
    }
}

// ---------------------------------------------------------------------------
extern "C" void kernel_launch(void* const* d_in, const int* in_sizes, int n_in,
                              void* d_out, int out_size, void* d_ws, size_t ws_size,
                              hipStream_t stream)
{
    const float* z     = (const float*)d_in[0];
    const float* in_w  = (const float*)d_in[1];
    const float* in_b  = (const float*)d_in[2];
    const float* out_w = (const float*)d_in[3];
    const float* out_b = (const float*)d_in[4];
    const float* cb    = (const float*)d_in[5];
    float* out = (float*)d_out;
    float* ws  = (float*)d_ws;

    k_prep<<<dim3(126), dim3(256), 0, stream>>>(in_w, out_w, out_b, cb, ws);
    k_prep_c<<<dim3(504), dim3(256), 0, stream>>>(cb, ws);
    k_pool_proj<<<dim3(16, 32), dim3(512), 0, stream>>>(z, in_w, in_b, ws);

    k_en<0><<<dim3(16), dim3(512), 0, stream>>>(ws, out);
    k_scan<0><<<dim3(8, 32), dim3(512), 0, stream>>>(ws);
    k_en<1><<<dim3(32), dim3(512), 0, stream>>>(ws, out);
    k_scan<1><<<dim3(4, 64), dim3(512), 0, stream>>>(ws);
    k_en<2><<<dim3(64), dim3(512), 0, stream>>>(ws, out);
    k_scan<2><<<dim3(2, 128), dim3(512), 0, stream>>>(ws);
    k_en<3><<<dim3(128), dim3(512), 0, stream>>>(ws, out);
    k_scan<3><<<dim3(1, 256), dim3(512), 0, stream>>>(ws);

    k_emit<<<dim3(480), dim3(256), 0, stream>>>(cb, ws, out);
    k_zq<<<dim3(4096), dim3(256), 0, stream>>>(out_w, cb, ws, out);
}

// Round 10
// 121.572 us; speedup vs baseline: 1.5310x; 1.3564x over previous
//
#include <hip/hip_runtime.h>

// ---------------------------------------------------------------------------
// MultiScaleResidualVectorQuantize: 4-stage residual VQ, strides (8,4,2,1)
// e_i = P_i - sum_{j<i} tab_ij[idx_j];  P_i = iw_i*pool_i(z)+ib_i;
// tab_ij[code] = M_ij*cb_j[code]+v_ij (f64 precompute, f32 table).
// 4 launches: prep -> pool(+tabgen) -> vq_all (fused cascade, block-local
// windows: gv_{S-1} = gv_S >> 1 exactly nests for NV_S = 32<<S, 256 blocks)
// -> zq. Fusion kills ~8 launch gaps and all cross-stage global round-trips.
// ---------------------------------------------------------------------------

constexpr int B = 16, D = 512, T = 4096, C = 8, K = 1024, NS = 4;

// output offsets (floats, reference return order)
constexpr long long OUT_ZQ     = 0;                       // 16*512*4096
constexpr long long OUT_LAT    = 33554432LL;              // 16*32*4096
constexpr long long OUT_COMMIT = OUT_LAT + 2097152LL;
constexpr long long OUT_CBL    = OUT_COMMIT + 1;
constexpr long long OUT_CODES0 = OUT_CBL + 1;

__host__ __device__ constexpr long long code_off(int j) {
    return OUT_CODES0 + (j >= 1 ? 8192 : 0) + (j >= 2 ? 16384 : 0) + (j >= 3 ? 32768 : 0);
}

// workspace offsets (floats / 4B units)
constexpr long long WS_CBREC = 0;                 // [4096][8] = -2*cn
constexpr long long WS_CN2   = 32768;             // [4096]
constexpr long long WS_OBS   = 36864;             // 512
constexpr long long WS_LOSS  = 37376;             // 1
constexpr long long WS_CORR  = 37384;             // 1152 doubles (8B aligned)
constexpr long long WS_P0    = 40960;             // 8192*8
constexpr long long WS_P1    = WS_P0 + 65536;
constexpr long long WS_P2    = WS_P1 + 131072;
constexpr long long WS_P3    = WS_P2 + 262144;
constexpr long long WS_TAB   = WS_P3 + 524288;    // 6*1024*8
constexpr long long WS_IDX   = WS_TAB + 49152;    // 122880 ints; ends ~4.8MB

__host__ __device__ constexpr long long idx_off(int s) {  // int units
    return (s >= 1 ? 8192 : 0) + (s >= 2 ? 16384 : 0) + (s >= 3 ? 32768 : 0);
}
__host__ __device__ constexpr long long pbase_of(int s) {
    return (s == 0) ? WS_P0 : (s == 1) ? WS_P1 : (s == 2) ? WS_P2 : WS_P3;
}

// ---------------------------------------------------------------------------
// k_prep: blocks 0..17 packed records (-2cn, cn2) + obs + loss=0;
// blocks 18..125 correction terms M_ij/v_ij (f64, one wave per scalar).
// ---------------------------------------------------------------------------
__global__ __launch_bounds__(256) void k_prep(
    const float* __restrict__ in_w, const float* __restrict__ out_w,
    const float* __restrict__ out_b, const float* __restrict__ cb,
    float* __restrict__ ws)
{
    int bid = blockIdx.x;
    int tid = threadIdx.x;

    if (bid < 18) {
        int t = bid * 256 + tid;
        if (t == 0) ws[WS_LOSS] = 0.f;
        if (t < NS * K) {
            const float* c = cb + (long long)t * 8;
            float cv[8];
#pragma unroll
            for (int k = 0; k < 8; k++) cv[k] = c[k];
            float n2 = 0.f;
#pragma unroll
            for (int k = 0; k < 8; k++) n2 += cv[k] * cv[k];
            float den = fmaxf(sqrtf(n2), 1e-12f);
            float cn[8];
#pragma unroll
            for (int k = 0; k < 8; k++) cn[k] = cv[k] / den;
            float cn2 = 0.f;
#pragma unroll
            for (int k = 0; k < 8; k++) cn2 = fmaf(cn[k], cn[k], cn2);
            float* r = ws + WS_CBREC + (long long)t * 8;
#pragma unroll
            for (int k = 0; k < 8; k++) r[k] = -2.0f * cn[k];
            ws[WS_CN2 + t] = cn2;
        } else if (t < NS * K + D) {
            int d = t - NS * K;
            ws[WS_OBS + d] = out_b[d] + out_b[512 + d] + out_b[1024 + d] + out_b[1536 + d];
        }
        return;
    }

    int gw = (bid - 18) * 4 + (tid >> 6);
    int lane = tid & 63;
    if (gw >= 6 * 72) return;
    int p = gw / 72, idx = gw % 72;
    int i, j;
    if (p == 0) { i = 1; j = 0; }
    else if (p < 3) { i = 2; j = p - 1; }
    else { i = 3; j = p - 3; }

    double acc = 0.0;
    if (idx < 64) {
        int ci = idx >> 3, cc = idx & 7;
        const float* wi = in_w + (long long)(i * 8 + ci) * 512;
        const float* wo = out_w + (long long)j * 4096;      // [d][8]
#pragma unroll
        for (int k = 0; k < 8; k++) {
            int d = lane + k * 64;
            acc += (double)wi[d] * (double)wo[d * 8 + cc];
        }
    } else {
        int ci = idx - 64;
        const float* wi = in_w + (long long)(i * 8 + ci) * 512;
        const float* bo = out_b + (long long)j * 512;
#pragma unroll
        for (int k = 0; k < 8; k++) {
            int d = lane + k * 64;
            acc += (double)wi[d] * (double)bo[d];
        }
    }
#pragma unroll
    for (int off = 32; off >= 1; off >>= 1) acc += __shfl_down(acc, off);
    if (lane == 0) ((double*)(ws + WS_CORR))[p * 72 + idx] = acc;
}

// ---------------------------------------------------------------------------
// k_pool_proj (proven R6 v3) + tabgen tail at blockIdx.y==32.
// ---------------------------------------------------------------------------
__global__ __launch_bounds__(512) void k_pool_proj(
    const float* __restrict__ z, const float* __restrict__ in_w,
    const float* __restrict__ in_b, const float* __restrict__ cb,
    float* __restrict__ ws)
{
    __shared__ float smem[512 * 36];     // 72 KB

    int tid = threadIdx.x;
    int lane = tid & 63;

    if (blockIdx.y == 32) {
        // tabgen: tab[p][code][c] = v[p][c] + M[p][c][:]*cb_j[code] (f64)
        int t = blockIdx.x * 512 + tid;
        if (t < 6 * 1024) {
            int p = t >> 10, code = t & 1023;
            int j = (p == 0) ? 0 : (p < 3) ? (p - 1) : (p - 3);
            const double* M = (const double*)(ws + WS_CORR) + p * 72;
            const float* q = cb + ((long long)j * K + code) * 8;
            float qv[8];
#pragma unroll
            for (int cc = 0; cc < 8; cc++) qv[cc] = q[cc];
            float* trow = ws + WS_TAB + (long long)t * 8;
#pragma unroll
            for (int c = 0; c < 8; c++) {
                double acc = M[64 + c];
#pragma unroll
                for (int cc = 0; cc < 8; cc++) acc += M[c * 8 + cc] * (double)qv[cc];
                trow[c] = (float)acc;
            }
        }
        return;
    }

    int wv = __builtin_amdgcn_readfirstlane(tid >> 6);
    int b = blockIdx.x;
    int t0 = blockIdx.y * 128;

#pragma unroll
    for (int sc = 0; sc < 32; ++sc)
        smem[tid * 36 + sc] = in_w[sc * 512 + tid];
    __syncthreads();

    const float* zrow = z + ((long long)b * D) * T + t0 + lane * 2;

    float a3[2][8] = {};
    float a2[8]    = {};
    float a1[8]    = {};
    float a0[8]    = {};

#pragma unroll 2
    for (int dd = 0; dd < 64; dd++) {
        int d = wv * 64 + dd;
        float2 v = *(const float2*)(zrow + (long long)d * T);
        const float* wrow = smem + d * 36;
        float w0[8], w1[8], w2[8], w3[8];
        *(float4*)&w0[0] = *(const float4*)(wrow + 0);
        *(float4*)&w0[4] = *(const float4*)(wrow + 4);
        *(float4*)&w1[0] = *(const float4*)(wrow + 8);
        *(float4*)&w1[4] = *(const float4*)(wrow + 12);
        *(float4*)&w2[0] = *(const float4*)(wrow + 16);
        *(float4*)&w2[4] = *(const float4*)(wrow + 20);
        *(float4*)&w3[0] = *(const float4*)(wrow + 24);
        *(float4*)&w3[4] = *(const float4*)(wrow + 28);

        float s2 = v.x + v.y;
#pragma unroll
        for (int c = 0; c < 8; c++) {
            a3[0][c] = fmaf(w3[c], v.x, a3[0][c]);
            a3[1][c] = fmaf(w3[c], v.y, a3[1][c]);
            a2[c]    = fmaf(w2[c], s2, a2[c]);
            a1[c]    = fmaf(w1[c], s2, a1[c]);
            a0[c]    = fmaf(w0[c], s2, a0[c]);
        }
    }

    __syncthreads();

    {
        float (*red)[16][64] = (float (*)[16][64])smem;
#pragma unroll
        for (int pos = 0; pos < 2; pos++)
#pragma unroll
            for (int c = 0; c < 8; c++)
                red[wv][pos * 8 + c][lane] = a3[pos][c];
        __syncthreads();
        for (int o = tid; o < 1024; o += 512) {
            int ln = o & 63, s = o >> 6;
            float sum = 0.f;
#pragma unroll
            for (int w = 0; w < 8; w++) sum += red[w][s][ln];
            int pos = s >> 3, c = s & 7;
            int tp = t0 + ln * 2 + pos;
            ws[WS_P3 + ((long long)b * 4096 + tp) * 8 + c] = sum + in_b[3 * 8 + c];
        }
        __syncthreads();
    }

    {
        float (*red)[24][64] = (float (*)[24][64])smem;
#pragma unroll
        for (int c = 0; c < 8; c++) {
            red[wv][c][lane]      = a2[c];
            red[wv][8 + c][lane]  = a1[c];
            red[wv][16 + c][lane] = a0[c];
        }
        __syncthreads();
        for (int o = tid; o < 1536; o += 512) {
            int ln = o & 63, s = o >> 6;
            if (s < 8) {
                int c = s;
                float sum = 0.f;
#pragma unroll
                for (int w = 0; w < 8; w++) sum += red[w][s][ln];
                int tp = (t0 >> 1) + ln;
                ws[WS_P2 + ((long long)b * 2048 + tp) * 8 + c] = sum * 0.5f + in_b[2 * 8 + c];
            } else if (s < 16) {
                if (ln >= 32) continue;
                int c = s - 8;
                float sum = 0.f;
#pragma unroll
                for (int w = 0; w < 8; w++) sum += red[w][s][2 * ln] + red[w][s][2 * ln + 1];
                int tp = (t0 >> 2) + ln;
                ws[WS_P1 + ((long long)b * 1024 + tp) * 8 + c] = sum * 0.25f + in_b[8 + c];
            } else {
                if (ln >= 16) continue;
                int c = s - 16;
                float sum = 0.f;
#pragma unroll
                for (int w = 0; w < 8; w++)
#pragma unroll
                    for (int k = 0; k < 4; k++) sum += red[w][s][4 * ln + k];
                int tp = (t0 >> 3) + ln;
                ws[WS_P0 + ((long long)b * 512 + tp) * 8 + c] = sum * 0.125f + in_b[c];
            }
        }
    }
}

// ---------------------------------------------------------------------------
// k_vq_all: fused 4-stage cascade. 256 blocks x 1024 thr (16 waves, 4/SIMD).
// Block owns nested windows: stage S vectors [bid*NV_S, (bid+1)*NV_S),
// NV_S = 32<<S; parent local idx = sv >> (S-j). Per stage: records->LDS,
// e-compute (tab f32 + f64 sub, idx from block LDS), 16 waves x 64-code
// scan (VPL<=4), LDS merge (exact first-index ties), coalesced latents,
// codes->out+ws, per-thread loss -> 1 atomic/block.
// ---------------------------------------------------------------------------
template <int S>
__device__ __forceinline__ void vq_stage_all(
    int tid, int lane, int w, int bid,
    const float* __restrict__ cb, float* __restrict__ ws, float* __restrict__ out,
    float* __restrict__ recl, float* __restrict__ cn2l,
    float (&e_lds)[256][8], float (&en_lds)[256][8],
    float (&sbl)[16][256], unsigned short (&sil)[16][256],
    int* __restrict__ idxl, float& loss_acc)
{
    constexpr int NV = 32 << S;
    constexpr int TS = 512 << S;
    constexpr long long PB = pbase_of(S);
    constexpr int pbase = (S == 1) ? 0 : (S == 2) ? 1 : 3;
    constexpr int VPL = (NV >= 64) ? (NV / 64) : 1;
    constexpr float LW = 1.0f / (float)(65536 << S);

    // A: stage records -> LDS (2 float4/thread + cn2)
    {
        const float4* rs = (const float4*)(ws + WS_CBREC + (long long)S * 8192);
        float4* rd = (float4*)recl;
        rd[tid] = rs[tid];
        rd[tid + 1024] = rs[tid + 1024];
        if (tid < 256)
            ((float4*)cn2l)[tid] = ((const float4*)(ws + WS_CN2 + (long long)S * 1024))[tid];
    }

    // B: e-compute (one thread per vector)
    if (tid < NV) {
        long long gv = (long long)bid * NV + tid;
        float e[8];
        const float* P = ws + PB + gv * 8;
        *(float4*)&e[0] = *(const float4*)(P + 0);
        *(float4*)&e[4] = *(const float4*)(P + 4);

        if constexpr (S > 0) {
            double ed[8];
#pragma unroll
            for (int c = 0; c < 8; c++) ed[c] = (double)e[c];
#pragma unroll
            for (int j = 0; j < S; j++) {
                int aj = tid >> (S - j);
                int cidx = idxl[((j == 0) ? 0 : (j == 1) ? 32 : 96) + aj];
                const float* trow = ws + WS_TAB + ((long long)(pbase + j) * 1024 + cidx) * 8;
#pragma unroll
                for (int c = 0; c < 8; c++) ed[c] -= (double)trow[c];
            }
#pragma unroll
            for (int c = 0; c < 8; c++) e[c] = (float)ed[c];
        }

        float n2 = 0.f;
#pragma unroll
        for (int c = 0; c < 8; c++) n2 = fmaf(e[c], e[c], n2);
        float den = fmaxf(sqrtf(n2), 1e-12f);
        float inv = 1.0f / den;
#pragma unroll
        for (int c = 0; c < 8; c++) {
            e_lds[tid][c] = e[c];
            en_lds[tid][c] = e[c] * inv;
        }
    }
    __syncthreads();   // recl, cn2l, e_lds, en_lds ready

    // C: latents (2048 floats, 2 per thread, coalesced float2)
    {
        constexpr int SREP = 8 >> S;
        constexpr int SH = 3 - S;
        long long gv0 = (long long)bid * NV;
        int b0 = (int)(gv0 >> (9 + S));
        int tp0 = (int)(gv0 & (TS - 1));
        long long lat0 = OUT_LAT + ((long long)b0 * 32 + S * 8) * T + (long long)tp0 * SREP;
        int o = tid * 2;
        int c = o >> 8, r = o & 255;
        *(float2*)(out + lat0 + (long long)c * T + r) =
            make_float2(e_lds[r >> SH][c], e_lds[(r + 1) >> SH][c]);
    }

    // D: scan -- wave w covers codes [w*64, w*64+64) for VPL vectors/lane
    float en_r[VPL][8];
#pragma unroll
    for (int v = 0; v < VPL; v++) {
        int sv = (NV >= 64) ? (v * 64 + lane) : (lane & (NV - 1));
#pragma unroll
        for (int c = 0; c < 8; c++) en_r[v][c] = en_lds[sv][c];
    }
    const float* rec = recl + w * 64 * 8;
    const float* c2 = cn2l + w * 64;
    float best[VPL];
    int bi[VPL];
#pragma unroll
    for (int v = 0; v < VPL; v++) { best[v] = 3.0e38f; bi[v] = 0; }

    for (int j0 = 0; j0 < 64; j0 += 4) {
        float4 cq = *(const float4*)(c2 + j0);
        float cqa[4] = { cq.x, cq.y, cq.z, cq.w };
#pragma unroll
        for (int k = 0; k < 4; k++) {
            int jt = j0 + k;
            const float* r = rec + jt * 8;
            float rr[8];
            *(float4*)&rr[0] = *(const float4*)(r + 0);
            *(float4*)&rr[4] = *(const float4*)(r + 4);
            float acc[VPL];
#pragma unroll
            for (int v = 0; v < VPL; v++) acc[v] = cqa[k];
#pragma unroll
            for (int c = 0; c < 8; c++) {
                float rc = rr[c];
#pragma unroll
                for (int v = 0; v < VPL; v++) acc[v] = fmaf(rc, en_r[v][c], acc[v]);
            }
#pragma unroll
            for (int v = 0; v < VPL; v++)
                if (acc[v] < best[v]) { best[v] = acc[v]; bi[v] = jt; }
        }
    }

    // E: per-wave results
#pragma unroll
    for (int v = 0; v < VPL; v++) {
        int sv = (NV >= 64) ? (v * 64 + lane) : (lane & (NV - 1));
        sbl[w][sv] = best[v];
        sil[w][sv] = (unsigned short)(w * 64 + bi[v]);
    }
    __syncthreads();

    // F: merge (exact first-index: w ascending = code ascending) + winner
    if (tid < NV) {
        float bd = sbl[0][tid];
        int bj = sil[0][tid];
#pragma unroll
        for (int ww = 1; ww < 16; ww++) {
            float d2 = sbl[ww][tid];
            int j2 = sil[ww][tid];
            if (d2 < bd || (d2 == bd && j2 < bj)) { bd = d2; bj = j2; }
        }
        if constexpr (S == 0) idxl[tid] = bj;
        else if constexpr (S == 1) idxl[32 + tid] = bj;
        else if constexpr (S == 2) idxl[96 + tid] = bj;

        long long gv = (long long)bid * NV + tid;
        out[code_off(S) + gv] = (float)bj;
        ((int*)ws)[WS_IDX + idx_off(S) + gv] = bj;

        const float* qc = cb + ((long long)S * K + bj) * 8;
        float l = 0.f;
#pragma unroll
        for (int c = 0; c < 8; c++) {
            float dq = e_lds[tid][c] - qc[c];
            l = fmaf(dq, dq, l);
        }
        loss_acc += l * LW;
    }
    __syncthreads();   // idxl ready for next stage; recl reusable
}

__global__ __launch_bounds__(1024) void k_vq_all(
    const float* __restrict__ cb, float* __restrict__ ws, float* __restrict__ out)
{
    __shared__ float recl[1024 * 8];        // 32 KB
    __shared__ float cn2l[1024];            // 4 KB
    __shared__ float e_lds[256][8];         // 8 KB
    __shared__ float en_lds[256][8];        // 8 KB
    __shared__ float sbl[16][256];          // 16 KB
    __shared__ unsigned short sil[16][256]; // 8 KB
    __shared__ int idxl[224];               // idx0 @0(32), idx1 @32(64), idx2 @96(128)
    __shared__ float lossw[16];

    int tid = threadIdx.x;
    int lane = tid & 63;
    int w = __builtin_amdgcn_readfirstlane(tid >> 6);
    int bid = blockIdx.x;
    float loss_acc = 0.f;

    vq_stage_all<0>(tid, lane, w, bid, cb, ws, out, recl, cn2l, e_lds, en_lds, sbl, sil, idxl, loss_acc);
    vq_stage_all<1>(tid, lane, w, bid, cb, ws, out, recl, cn2l, e_lds, en_lds, sbl, sil, idxl, loss_acc);
    vq_stage_all<2>(tid, lane, w, bid, cb, ws, out, recl, cn2l, e_lds, en_lds, sbl, sil, idxl, loss_acc);
    vq_stage_all<3>(tid, lane, w, bid, cb, ws, out, recl, cn2l, e_lds, en_lds, sbl, sil, idxl, loss_acc);

    // block loss reduce -> one atomic
#pragma unroll
    for (int off = 32; off >= 1; off >>= 1) loss_acc += __shfl_down(loss_acc, off);
    if (lane == 0) lossw[w] = loss_acc;
    __syncthreads();
    if (tid == 0) {
        float s = 0.f;
#pragma unroll
        for (int i = 0; i < 16; i++) s += lossw[i];
        atomicAdd(ws + WS_LOSS, s);
    }
}

// ---------------------------------------------------------------------------
// k_zq: lane owns 4 consecutive t -> float4 stores; q gathered from cb via
// int idx arrays. 4096 blocks. Same per-element FMA chain (bit-identical).
// ---------------------------------------------------------------------------
__global__ __launch_bounds__(256) void k_zq(
    const float* __restrict__ out_w, const float* __restrict__ cb,
    const float* __restrict__ ws, float* __restrict__ out)
{
    int tid = threadIdx.x;
    int lane = tid & 63;
    int w = __builtin_amdgcn_readfirstlane(tid >> 6);
    int bid = blockIdx.x;                 // 4096 = 16 b * 64 dgrp * 4 tchunk
    int tc   = bid & 3;
    int g    = (bid >> 2) & 63;
    int b    = bid >> 8;
    int t    = tc * 1024 + w * 256 + lane * 4;

    const int* wsi = (const int*)ws;

    float q0[8], q1[8], q2[2][8], q3[4][8];
    {
        int bj = wsi[WS_IDX + idx_off(0) + (long long)b * 512 + (t >> 3)];
        const float* Q = cb + (long long)bj * 8;
#pragma unroll
        for (int c = 0; c < 8; c++) q0[c] = Q[c];
    }
    {
        int bj = wsi[WS_IDX + idx_off(1) + (long long)b * 1024 + (t >> 2)];
        const float* Q = cb + (long long)(K + bj) * 8;
#pragma unroll
        for (int c = 0; c < 8; c++) q1[c] = Q[c];
    }
#pragma unroll
    for (int j = 0; j < 2; j++) {
        int bj = wsi[WS_IDX + idx_off(2) + (long long)b * 2048 + (t >> 1) + j];
        const float* Q = cb + (long long)(2 * K + bj) * 8;
#pragma unroll
        for (int c = 0; c < 8; c++) q2[j][c] = Q[c];
    }
#pragma unroll
    for (int j = 0; j < 4; j++) {
        int bj = wsi[WS_IDX + idx_off(3) + (long long)b * 4096 + t + j];
        const float* Q = cb + (long long)(3 * K + bj) * 8;
#pragma unroll
        for (int c = 0; c < 8; c++) q3[j][c] = Q[c];
    }

#pragma unroll 2
    for (int dl = 0; dl < 8; dl++) {
        int d = g * 8 + dl;
        const float* w0 = out_w + 0 * 4096 + d * 8;
        const float* w1 = out_w + 1 * 4096 + d * 8;
        const float* w2 = out_w + 2 * 4096 + d * 8;
        const float* w3 = out_w + 3 * 4096 + d * 8;

        float acc = ws[WS_OBS + d];
#pragma unroll
        for (int c = 0; c < 8; c++) acc = fmaf(w0[c], q0[c], acc);
#pragma unroll
        for (int c = 0; c < 8; c++) acc = fmaf(w1[c], q1[c], acc);
        float accA = acc, accB = acc;
#pragma unroll
        for (int c = 0; c < 8; c++) {
            accA = fmaf(w2[c], q2[0][c], accA);
            accB = fmaf(w2[c], q2[1][c], accB);
        }
        float r0 = accA, r1 = accA, r2 = accB, r3 = accB;
#pragma unroll
        for (int c = 0; c < 8; c++) {
            r0 = fmaf(w3[c], q3[0][c], r0);
            r1 = fmaf(w3[c], q3[1][c], r1);
            r2 = fmaf(w3[c], q3[2][c], r2);
            r3 = fmaf(w3[c], q3[3][c], r3);
        }
        float* o = out + OUT_ZQ + ((long long)b * 512 + d) * T + t;
        *(float4*)o = make_float4(r0, r1, r2, r3);
    }

    if (bid == 0 && tid == 0) {
        float L = ws[WS_LOSS];
        out[OUT_COMMIT] = L;
        out[OUT_CBL]    = L;
    }
}

// ---------------------------------------------------------------------------
extern "C" void kernel_launch(void* const* d_in, const int* in_sizes, int n_in,
                              void* d_out, int out_size, void* d_ws, size_t ws_size,
                              hipStream_t stream)
{
    const float* z     = (const float*)d_in[0];
    const float* in_w  = (const float*)d_in[1];
    const float* in_b  = (const float*)d_in[2];
    const float* out_w = (const float*)d_in[3];
    const float* out_b = (const float*)d_in[4];
    const float* cb    = (const float*)d_in[5];
    float* out = (float*)d_out;
    float* ws  = (float*)d_ws;

    k_prep<<<dim3(126), dim3(256), 0, stream>>>(in_w, out_w, out_b, cb, ws);
    k_pool_proj<<<dim3(16, 33), dim3(512), 0, stream>>>(z, in_w, in_b, cb, ws);
    k_vq_all<<<dim3(256), dim3(1024), 0, stream>>>(cb, ws, out);
    k_zq<<<dim3(4096), dim3(256), 0, stream>>>(out_w, cb, ws, out);
}